// Round 7
// baseline (342.078 us; speedup 1.0000x reference)
//
#include <hip/hip_runtime.h>
#include <hip/hip_fp16.h>

typedef _Float16 f16x8 __attribute__((ext_vector_type(8)));
typedef _Float16 f16x4 __attribute__((ext_vector_type(4)));
typedef float    f32x4 __attribute__((ext_vector_type(4)));

#define BATCH 131072

// ---------------------------------------------------------------------------
// Kernel 1: synthesize W_i[k][n] = tri(dist(p_i[k], p_{i+1}[n])) / sqrt(K),
// stored TRANSPOSED as Wt[n][k] f16. k fast-varying -> coalesced writes.
// ---------------------------------------------------------------------------
__global__ void synth_weights_kernel(const float* __restrict__ p0, const float* __restrict__ p1,
                                     const float* __restrict__ p2, const float* __restrict__ p3,
                                     _Float16* __restrict__ wt0, _Float16* __restrict__ wt1,
                                     _Float16* __restrict__ wt2)
{
    int idx = blockIdx.x * blockDim.x + threadIdx.x;   // 524288 total, exact grid
    const float* A; const float* B; _Float16* Wt; float scl; int e, k, n;
    if (idx < 131072)      { A = p0; B = p1; Wt = wt0; scl = 0.0625f;              e = idx;          k = e & 255; n = e >> 8; }
    else if (idx < 393216) { A = p1; B = p2; Wt = wt1; scl = 0.04419417382415922f; e = idx - 131072; k = e & 511; n = e >> 9; }
    else                   { A = p2; B = p3; Wt = wt2; scl = 0.04419417382415922f; e = idx - 393216; k = e & 511; n = e >> 9; }
    float d2 = 0.f;
#pragma unroll
    for (int t = 0; t < 20; ++t) {
        float df = A[k * 20 + t] - B[n * 20 + t];
        d2 += df * df;
    }
    float d  = sqrtf(d2);
    float md = fmodf(d, 0.2f);                            // period 2P = 0.2, d >= 0
    float w  = 10.0f * (0.05f - fabsf(md - 0.1f)) * scl;  // AMP/P*(P-|m-P|-P/2)/sqrt(K)
    Wt[(size_t)e] = (_Float16)w;                          // e == n*K + k
}

// ---------------------------------------------------------------------------
// Fused MLP v7: 1024 threads, 128 rows/block, LDS = act slab ONLY (128 KB).
// Weights stream global(L2) -> registers with 1-window-deep double rotation
// (wfA/wfB); NO per-window barriers -- waves free-run through the k-loop.
// Act rows 1024 B, 16B-chunk swizzle c ^ (row&7); z stored in-place between
// layers (2 barriers per layer boundary only).
// frag layouts (16x16x32, HW-verified R1-R6):
//   A/B input: index = lane&15, k = (lane>>4)*8 + j
//   D (swapped: mfma(wf, xf)): m = lane&15, n = (lane>>4)*4 + q (+16*ni)
// ---------------------------------------------------------------------------
template<int K, int NI, int MI>
__device__ __forceinline__ void mm_stream(const char* act, const _Float16* __restrict__ Wt,
                                          int wr, int wc, int lane, f32x4 (&acc)[NI][MI])
{
    constexpr int NW = K / 32;            // 32-k windows (8 or 16, even)
    const int rl = lane & 15;
    const int hi = lane >> 4;

    const _Float16* wp[NI];
#pragma unroll
    for (int ni = 0; ni < NI; ++ni)
        wp[ni] = Wt + (size_t)(wc + ni * 16 + rl) * K + hi * 8;

    f16x8 wfA[NI], wfB[NI];
#pragma unroll
    for (int ni = 0; ni < NI; ++ni) wfA[ni] = *(const f16x8*)(wp[ni]);

#pragma unroll 1
    for (int w = 0; w < NW; w += 2) {
        // issue window w+1 (always exists: NW even)
#pragma unroll
        for (int ni = 0; ni < NI; ++ni)
            wfB[ni] = *(const f16x8*)(wp[ni] + (w + 1) * 32);
        {
            f16x8 xf[MI];
#pragma unroll
            for (int mi = 0; mi < MI; ++mi) {
                const int row = wr + mi * 16 + rl;
                const int c   = w * 4 + hi;
                xf[mi] = *(const f16x8*)(act + row * 1024 + ((c ^ (row & 7)) << 4));
            }
            __builtin_amdgcn_s_setprio(1);
#pragma unroll
            for (int ni = 0; ni < NI; ++ni)
#pragma unroll
                for (int mi = 0; mi < MI; ++mi)
                    acc[ni][mi] = __builtin_amdgcn_mfma_f32_16x16x32_f16(wfA[ni], xf[mi], acc[ni][mi], 0, 0, 0);
            __builtin_amdgcn_s_setprio(0);
        }
        // issue window w+2 into wfA
        if (w + 2 < NW) {
#pragma unroll
            for (int ni = 0; ni < NI; ++ni)
                wfA[ni] = *(const f16x8*)(wp[ni] + (w + 2) * 32);
        }
        {
            f16x8 xf[MI];
#pragma unroll
            for (int mi = 0; mi < MI; ++mi) {
                const int row = wr + mi * 16 + rl;
                const int c   = (w + 1) * 4 + hi;
                xf[mi] = *(const f16x8*)(act + row * 1024 + ((c ^ (row & 7)) << 4));
            }
            __builtin_amdgcn_s_setprio(1);
#pragma unroll
            for (int ni = 0; ni < NI; ++ni)
#pragma unroll
                for (int mi = 0; mi < MI; ++mi)
                    acc[ni][mi] = __builtin_amdgcn_mfma_f32_16x16x32_f16(wfB[ni], xf[mi], acc[ni][mi], 0, 0, 0);
            __builtin_amdgcn_s_setprio(0);
        }
    }
}

// Write z (bias+relu) into act LDS [128][1024B] as 8B packs of 4 consecutive n.
template<int NI, int MI>
__device__ __forceinline__ void store_z(char* act, const float* __restrict__ bias,
                                        int wr, int wc, int lane, f32x4 (&acc)[NI][MI])
{
    const int rl = lane & 15;
    const int hi = lane >> 4;
#pragma unroll
    for (int ni = 0; ni < NI; ++ni) {
        const int n0 = wc + ni * 16 + hi * 4;
        const float4 bv = *(const float4*)(bias + n0);
#pragma unroll
        for (int mi = 0; mi < MI; ++mi) {
            const int m = wr + mi * 16 + rl;
            f16x4 h;
            h[0] = (_Float16)fmaxf(acc[ni][mi][0] + bv.x, 0.0f);
            h[1] = (_Float16)fmaxf(acc[ni][mi][1] + bv.y, 0.0f);
            h[2] = (_Float16)fmaxf(acc[ni][mi][2] + bv.z, 0.0f);
            h[3] = (_Float16)fmaxf(acc[ni][mi][3] + bv.w, 0.0f);
            *(f16x4*)(act + m * 1024 + (((n0 >> 3) ^ (m & 7)) << 4) + (n0 & 7) * 2) = h;
        }
    }
}

__global__ __launch_bounds__(1024, 4)
void fused_mlp_kernel(const float* __restrict__ x,
                      const _Float16* __restrict__ wt0, const _Float16* __restrict__ wt1,
                      const _Float16* __restrict__ wt2,
                      const float* __restrict__ b1, const float* __restrict__ b2,
                      const float* __restrict__ b3,
                      float* __restrict__ out)
{
    extern __shared__ char act[];             // 128 KB act slab only
    const int tid  = threadIdx.x;
    const int lane = tid & 63;
    const int wid  = tid >> 6;
    const size_t m0 = (size_t)blockIdx.x * 128;

    // ---- stage x slab f32 -> f16 into act [128 rows][1024 B stride, 512 used]
#pragma unroll
    for (int it = 0; it < 4; ++it) {
        const int c   = it * 1024 + tid;      // 4096 16B-chunks
        const int row = c >> 5;
        const int c8  = c & 31;
        const float* src = x + (m0 + row) * 256 + c8 * 8;
        const float4 v0 = *(const float4*)src;
        const float4 v1 = *(const float4*)(src + 4);
        f16x8 h;
        h[0] = (_Float16)v0.x; h[1] = (_Float16)v0.y; h[2] = (_Float16)v0.z; h[3] = (_Float16)v0.w;
        h[4] = (_Float16)v1.x; h[5] = (_Float16)v1.y; h[6] = (_Float16)v1.z; h[7] = (_Float16)v1.w;
        *(f16x8*)(act + row * 1024 + ((c8 ^ (row & 7)) << 4)) = h;
    }
    __syncthreads();

    // wave tiling L1/L2: 16 waves = 2m x 8n of (64m x 64n)
    const int wr = (wid >> 3) * 64;
    const int wc = (wid & 7) * 64;

    // ---- layer 1: z1 = relu(x @ W0 + b1)   [128,256]@[256,512]
    {
        f32x4 acc[4][4] = {};
        mm_stream<256, 4, 4>(act, wt0, wr, wc, lane, acc);
        __syncthreads();                      // all waves done reading x
        store_z(act, b1, wr, wc, lane, acc);
        __syncthreads();
    }

    // ---- layer 2: z2 = relu(z1 @ W1 + b2)  [128,512]@[512,512]  (in-place)
    {
        f32x4 acc[4][4] = {};
        mm_stream<512, 4, 4>(act, wt1, wr, wc, lane, acc);
        __syncthreads();
        store_z(act, b2, wr, wc, lane, acc);
        __syncthreads();
    }

    // ---- layer 3: out = z2 @ W2 + b3       [128,512]@[512,256], direct f32
    {
        const int wr3 = (wid & 3) * 32;       // 4m x 4n of (32m x 64n)
        const int wc3 = (wid >> 2) * 64;
        f32x4 acc[4][2] = {};
        mm_stream<512, 4, 2>(act, wt2, wr3, wc3, lane, acc);

        const int rl = lane & 15;
        const int hi = lane >> 4;
#pragma unroll
        for (int ni = 0; ni < 4; ++ni) {
            const int n0 = wc3 + ni * 16 + hi * 4;
            const float4 bv = *(const float4*)(b3 + n0);
#pragma unroll
            for (int mi = 0; mi < 2; ++mi) {
                const size_t m = m0 + wr3 + mi * 16 + rl;
                f32x4 o;
                o[0] = acc[ni][mi][0] + bv.x;
                o[1] = acc[ni][mi][1] + bv.y;
                o[2] = acc[ni][mi][2] + bv.z;
                o[3] = acc[ni][mi][3] + bv.w;
                *(f32x4*)(out + m * 256 + n0) = o;
            }
        }
    }
}

// ---------------------------------------------------------------------------
// kernel_launch — ws: [wt0 512x256 f16 | wt1 512x512 f16 | wt2 256x512 f16]
// ---------------------------------------------------------------------------
extern "C" void kernel_launch(void* const* d_in, const int* in_sizes, int n_in,
                              void* d_out, int out_size, void* d_ws, size_t ws_size,
                              hipStream_t stream)
{
    const float* x  = (const float*)d_in[0];
    const float* p0 = (const float*)d_in[1];
    const float* p1 = (const float*)d_in[2];
    const float* p2 = (const float*)d_in[3];
    const float* p3 = (const float*)d_in[4];
    const float* b1 = (const float*)d_in[5];
    const float* b2 = (const float*)d_in[6];
    const float* b3 = (const float*)d_in[7];

    char* ws = (char*)d_ws;
    _Float16* wt0 = (_Float16*)(ws);                    // 262144 B
    _Float16* wt1 = (_Float16*)(ws + 262144);           // 524288 B
    _Float16* wt2 = (_Float16*)(ws + 262144 + 524288);  // 262144 B

    synth_weights_kernel<<<2048, 256, 0, stream>>>(p0, p1, p2, p3, wt0, wt1, wt2);

    fused_mlp_kernel<<<BATCH / 128, 1024, 131072, stream>>>(x, wt0, wt1, wt2, b1, b2, b3,
                                                            (float*)d_out);
}

// Round 8
// 239.770 us; speedup vs baseline: 1.4267x; 1.4267x over previous
//
#include <hip/hip_runtime.h>
#include <hip/hip_fp16.h>

typedef _Float16 f16x8 __attribute__((ext_vector_type(8)));
typedef _Float16 f16x4 __attribute__((ext_vector_type(4)));
typedef float    f32x4 __attribute__((ext_vector_type(4)));

#define BATCH 131072

// ---------------------------------------------------------------------------
// Kernel 1: synthesize W_i[k][n] = tri(dist(p_i[k], p_{i+1}[n])) / sqrt(K),
// stored TRANSPOSED as Wt[n][k] f16. k fast-varying -> coalesced writes.
// ---------------------------------------------------------------------------
__global__ void synth_weights_kernel(const float* __restrict__ p0, const float* __restrict__ p1,
                                     const float* __restrict__ p2, const float* __restrict__ p3,
                                     _Float16* __restrict__ wt0, _Float16* __restrict__ wt1,
                                     _Float16* __restrict__ wt2)
{
    int idx = blockIdx.x * blockDim.x + threadIdx.x;   // 524288 total, exact grid
    const float* A; const float* B; _Float16* Wt; float scl; int e, k, n;
    if (idx < 131072)      { A = p0; B = p1; Wt = wt0; scl = 0.0625f;              e = idx;          k = e & 255; n = e >> 8; }
    else if (idx < 393216) { A = p1; B = p2; Wt = wt1; scl = 0.04419417382415922f; e = idx - 131072; k = e & 511; n = e >> 9; }
    else                   { A = p2; B = p3; Wt = wt2; scl = 0.04419417382415922f; e = idx - 393216; k = e & 511; n = e >> 9; }
    float d2 = 0.f;
#pragma unroll
    for (int t = 0; t < 20; ++t) {
        float df = A[k * 20 + t] - B[n * 20 + t];
        d2 += df * df;
    }
    float d  = sqrtf(d2);
    float md = fmodf(d, 0.2f);                            // period 2P = 0.2, d >= 0
    float w  = 10.0f * (0.05f - fabsf(md - 0.1f)) * scl;  // AMP/P*(P-|m-P|-P/2)/sqrt(K)
    Wt[(size_t)e] = (_Float16)w;                          // e == n*K + k
}

// ---------------------------------------------------------------------------
// Fused MLP v8: 512 threads (8 waves), 128 rows/block, LDS = act slab ONLY.
// Grid 1m x 8n: wave tile = 128m x 64n (L1/L2) or 128m x 32n (L3).
//   - B (weights): global(L2) -> registers, each weight row loaded ONCE per
//     block (B-redundancy 1). Double-buffered window ring wfA/wfB; prefetch
//     slack = one full 32-MFMA cluster (~600 cyc) >> L2 latency.
//   - A (acts): LDS slab [128][1024B], 16B-chunk swizzle c ^ (row&7);
//     xf frags double-buffered xfA/xfB.
//   - NO barriers inside the k-loop (act read-only per layer, B in regs).
//     Barriers only around store_z at layer boundaries.
// frag layouts (16x16x32, HW-verified R1-R7):
//   A/B input: index = lane&15, k = (lane>>4)*8 + j
//   D (swapped: mfma(wf, xf)): m = lane&15, n = (lane>>4)*4 + q (+16*ni)
// ---------------------------------------------------------------------------
__device__ __forceinline__ f16x8 ld_act(const char* act, int mi, int rl, int hi, int w)
{
    const int row = mi * 16 + rl;
    const int c   = w * 4 + hi;
    return *(const f16x8*)(act + row * 1024 + ((c ^ (row & 7)) << 4));
}

template<int K, int NI, int MI>
__device__ __forceinline__ void mm_reg(const char* act, const _Float16* __restrict__ Wt,
                                       int wc, int lane, f32x4 (&acc)[NI][MI])
{
    constexpr int NW = K / 32;            // 32-k windows: 8 or 16 (even)
    const int rl = lane & 15;
    const int hi = lane >> 4;

    const _Float16* wp[NI];
#pragma unroll
    for (int ni = 0; ni < NI; ++ni)
        wp[ni] = Wt + (size_t)(wc + ni * 16 + rl) * K + hi * 8;

    f16x8 wfA[NI], wfB[NI], xfA[MI], xfB[MI];

    // prologue: window 0 into the A set
#pragma unroll
    for (int ni = 0; ni < NI; ++ni) wfA[ni] = *(const f16x8*)(wp[ni]);
#pragma unroll
    for (int mi = 0; mi < MI; ++mi) xfA[mi] = ld_act(act, mi, rl, hi, 0);

#pragma unroll
    for (int w = 0; w < NW; w += 2) {
        // prefetch w+1 into B set (always valid: NW even), then compute A set
#pragma unroll
        for (int ni = 0; ni < NI; ++ni) wfB[ni] = *(const f16x8*)(wp[ni] + (w + 1) * 32);
#pragma unroll
        for (int mi = 0; mi < MI; ++mi) xfB[mi] = ld_act(act, mi, rl, hi, w + 1);
        __builtin_amdgcn_s_setprio(1);
#pragma unroll
        for (int ni = 0; ni < NI; ++ni)
#pragma unroll
            for (int mi = 0; mi < MI; ++mi)
                acc[ni][mi] = __builtin_amdgcn_mfma_f32_16x16x32_f16(wfA[ni], xfA[mi], acc[ni][mi], 0, 0, 0);
        __builtin_amdgcn_s_setprio(0);

        // prefetch w+2 into A set, then compute B set
        if (w + 2 < NW) {
#pragma unroll
            for (int ni = 0; ni < NI; ++ni) wfA[ni] = *(const f16x8*)(wp[ni] + (w + 2) * 32);
#pragma unroll
            for (int mi = 0; mi < MI; ++mi) xfA[mi] = ld_act(act, mi, rl, hi, w + 2);
        }
        __builtin_amdgcn_s_setprio(1);
#pragma unroll
        for (int ni = 0; ni < NI; ++ni)
#pragma unroll
            for (int mi = 0; mi < MI; ++mi)
                acc[ni][mi] = __builtin_amdgcn_mfma_f32_16x16x32_f16(wfB[ni], xfB[mi], acc[ni][mi], 0, 0, 0);
        __builtin_amdgcn_s_setprio(0);
    }
}

// Write z (bias+relu) into act LDS [128][1024B] as 8B packs of 4 consecutive n.
// Bank check: 8 (m&7) x 2 chx x 2 n-bit -> 32 banks, 2 lanes/bank (free).
template<int NI, int MI>
__device__ __forceinline__ void store_z(char* act, const float* __restrict__ bias,
                                        int wc, int lane, f32x4 (&acc)[NI][MI])
{
    const int rl = lane & 15;
    const int hi = lane >> 4;
#pragma unroll
    for (int ni = 0; ni < NI; ++ni) {
        const int n0 = wc + ni * 16 + hi * 4;
        const float4 bv = *(const float4*)(bias + n0);
#pragma unroll
        for (int mi = 0; mi < MI; ++mi) {
            const int m = mi * 16 + rl;
            f16x4 h;
            h[0] = (_Float16)fmaxf(acc[ni][mi][0] + bv.x, 0.0f);
            h[1] = (_Float16)fmaxf(acc[ni][mi][1] + bv.y, 0.0f);
            h[2] = (_Float16)fmaxf(acc[ni][mi][2] + bv.z, 0.0f);
            h[3] = (_Float16)fmaxf(acc[ni][mi][3] + bv.w, 0.0f);
            *(f16x4*)(act + m * 1024 + (((n0 >> 3) ^ (m & 7)) << 4) + (n0 & 7) * 2) = h;
        }
    }
}

__global__ __launch_bounds__(512, 2)
void fused_mlp_kernel(const float* __restrict__ x,
                      const _Float16* __restrict__ wt0, const _Float16* __restrict__ wt1,
                      const _Float16* __restrict__ wt2,
                      const float* __restrict__ b1, const float* __restrict__ b2,
                      const float* __restrict__ b3,
                      float* __restrict__ out)
{
    extern __shared__ char act[];             // 128 KB act slab only
    const int tid  = threadIdx.x;
    const int lane = tid & 63;
    const int wid  = tid >> 6;                // 0..7
    const size_t m0 = (size_t)blockIdx.x * 128;

    // ---- stage x slab f32 -> f16 into act [128 rows][1024 B stride, 512 used]
#pragma unroll
    for (int it = 0; it < 8; ++it) {
        const int c   = it * 512 + tid;       // 4096 16B-chunks
        const int row = c >> 5;
        const int c8  = c & 31;
        const float* src = x + (m0 + row) * 256 + c8 * 8;
        const float4 v0 = *(const float4*)src;
        const float4 v1 = *(const float4*)(src + 4);
        f16x8 h;
        h[0] = (_Float16)v0.x; h[1] = (_Float16)v0.y; h[2] = (_Float16)v0.z; h[3] = (_Float16)v0.w;
        h[4] = (_Float16)v1.x; h[5] = (_Float16)v1.y; h[6] = (_Float16)v1.z; h[7] = (_Float16)v1.w;
        *(f16x8*)(act + row * 1024 + ((c8 ^ (row & 7)) << 4)) = h;
    }
    __syncthreads();

    const int wc = wid * 64;                  // wave's exclusive 64-n panel (L1/L2)

    // ---- layer 1: z1 = relu(x @ W0 + b1)   [128,256]@[256,512]
    {
        f32x4 acc[4][8] = {};
        mm_reg<256, 4, 8>(act, wt0, wc, lane, acc);
        __syncthreads();                      // all waves done reading x
        store_z<4, 8>(act, b1, wc, lane, acc);
        __syncthreads();
    }

    // ---- layer 2: z2 = relu(z1 @ W1 + b2)  [128,512]@[512,512]  (in-place)
    {
        f32x4 acc[4][8] = {};
        mm_reg<512, 4, 8>(act, wt1, wc, lane, acc);
        __syncthreads();
        store_z<4, 8>(act, b2, wc, lane, acc);
        __syncthreads();
    }

    // ---- layer 3: out = z2 @ W2 + b3       [128,512]@[512,256], direct f32
    {
        const int wc3 = wid * 32;             // wave's exclusive 32-n panel
        f32x4 acc[2][8] = {};
        mm_reg<512, 2, 8>(act, wt2, wc3, lane, acc);

        const int rl = lane & 15;
        const int hi = lane >> 4;
#pragma unroll
        for (int ni = 0; ni < 2; ++ni) {
            const int n0 = wc3 + ni * 16 + hi * 4;
            const float4 bv = *(const float4*)(b3 + n0);
#pragma unroll
            for (int mi = 0; mi < 8; ++mi) {
                const size_t m = m0 + mi * 16 + rl;
                f32x4 o;
                o[0] = acc[ni][mi][0] + bv.x;
                o[1] = acc[ni][mi][1] + bv.y;
                o[2] = acc[ni][mi][2] + bv.z;
                o[3] = acc[ni][mi][3] + bv.w;
                *(f32x4*)(out + m * 256 + n0) = o;
            }
        }
    }
}

// ---------------------------------------------------------------------------
// kernel_launch — ws: [wt0 512x256 f16 | wt1 512x512 f16 | wt2 256x512 f16]
// ---------------------------------------------------------------------------
extern "C" void kernel_launch(void* const* d_in, const int* in_sizes, int n_in,
                              void* d_out, int out_size, void* d_ws, size_t ws_size,
                              hipStream_t stream)
{
    const float* x  = (const float*)d_in[0];
    const float* p0 = (const float*)d_in[1];
    const float* p1 = (const float*)d_in[2];
    const float* p2 = (const float*)d_in[3];
    const float* p3 = (const float*)d_in[4];
    const float* b1 = (const float*)d_in[5];
    const float* b2 = (const float*)d_in[6];
    const float* b3 = (const float*)d_in[7];

    char* ws = (char*)d_ws;
    _Float16* wt0 = (_Float16*)(ws);                    // 262144 B
    _Float16* wt1 = (_Float16*)(ws + 262144);           // 524288 B
    _Float16* wt2 = (_Float16*)(ws + 262144 + 524288);  // 262144 B

    synth_weights_kernel<<<2048, 256, 0, stream>>>(p0, p1, p2, p3, wt0, wt1, wt2);

    fused_mlp_kernel<<<BATCH / 128, 512, 131072, stream>>>(x, wt0, wt1, wt2, b1, b2, b3,
                                                           (float*)d_out);
}

// Round 9
// 187.710 us; speedup vs baseline: 1.8224x; 1.2773x over previous
//
#include <hip/hip_runtime.h>
#include <hip/hip_fp16.h>

typedef _Float16 f16x8 __attribute__((ext_vector_type(8)));
typedef _Float16 f16x4 __attribute__((ext_vector_type(4)));
typedef float    f32x4 __attribute__((ext_vector_type(4)));

#define BATCH 131072

// ---------------------------------------------------------------------------
// Kernel 1: synthesize W_i[k][n] = tri(dist(p_i[k], p_{i+1}[n])) / sqrt(K),
// stored TRANSPOSED as Wt[n][k] f16. k fast-varying -> coalesced writes.
// ---------------------------------------------------------------------------
__global__ void synth_weights_kernel(const float* __restrict__ p0, const float* __restrict__ p1,
                                     const float* __restrict__ p2, const float* __restrict__ p3,
                                     _Float16* __restrict__ wt0, _Float16* __restrict__ wt1,
                                     _Float16* __restrict__ wt2)
{
    int idx = blockIdx.x * blockDim.x + threadIdx.x;   // 524288 total, exact grid
    const float* A; const float* B; _Float16* Wt; float scl; int e, k, n;
    if (idx < 131072)      { A = p0; B = p1; Wt = wt0; scl = 0.0625f;              e = idx;          k = e & 255; n = e >> 8; }
    else if (idx < 393216) { A = p1; B = p2; Wt = wt1; scl = 0.04419417382415922f; e = idx - 131072; k = e & 511; n = e >> 9; }
    else                   { A = p2; B = p3; Wt = wt2; scl = 0.04419417382415922f; e = idx - 393216; k = e & 511; n = e >> 9; }
    float d2 = 0.f;
#pragma unroll
    for (int t = 0; t < 20; ++t) {
        float df = A[k * 20 + t] - B[n * 20 + t];
        d2 += df * df;
    }
    float d  = sqrtf(d2);
    float md = fmodf(d, 0.2f);                            // period 2P = 0.2, d >= 0
    float w  = 10.0f * (0.05f - fabsf(md - 0.1f)) * scl;  // AMP/P*(P-|m-P|-P/2)/sqrt(K)
    Wt[(size_t)e] = (_Float16)w;                          // e == n*K + k
}

// ---------------------------------------------------------------------------
// Fused MLP v9: 512 threads (8 waves), 128 rows/block, LDS = act slab ONLY.
// Wave tile = 128m x 64n (L1/L2) or 128m x 32n (L3); B-redundancy = 1.
//   - wf (weights): global(L2) -> reg, double-buffered one window deep
//     (32-MFMA cluster ~620 cyc >> L2 latency ~300 cyc).
//   - xf (acts): single-buffered LDS reads right before the MFMA cluster
//     (lgkmcnt hidden inside cluster). Register-feasible: acc 128 (AGPR)
//     + wf 32 + xf 32 + ptrs ~10 < 256-reg budget at 2 waves/SIMD.
//   - NO barriers in the k-loop; barriers only around store_z.
// frag layouts (16x16x32, HW-verified R1-R8):
//   A/B input: index = lane&15, k = (lane>>4)*8 + j
//   D (swapped: mfma(wf, xf)): m = lane&15, n = (lane>>4)*4 + q (+16*ni)
// ---------------------------------------------------------------------------
__device__ __forceinline__ f16x8 ld_act(const char* act, int mi, int rl, int hi, int w)
{
    const int row = mi * 16 + rl;
    const int c   = w * 4 + hi;
    return *(const f16x8*)(act + row * 1024 + ((c ^ (row & 7)) << 4));
}

template<int K, int NI, int MI>
__device__ __forceinline__ void mm_reg(const char* act, const _Float16* __restrict__ Wt,
                                       int wc, int lane, f32x4 (&acc)[NI][MI])
{
    constexpr int NW = K / 32;            // 32-k windows: 8 or 16 (even)
    const int rl = lane & 15;
    const int hi = lane >> 4;

    const _Float16* wp[NI];
#pragma unroll
    for (int ni = 0; ni < NI; ++ni)
        wp[ni] = Wt + (size_t)(wc + ni * 16 + rl) * K + hi * 8;

    f16x8 wfA[NI], wfB[NI];
#pragma unroll
    for (int ni = 0; ni < NI; ++ni) wfA[ni] = *(const f16x8*)(wp[ni]);   // window 0

#pragma unroll 1
    for (int w = 0; w < NW; w += 2) {
        // issue global prefetch of window w+1 (NW even -> always valid)
#pragma unroll
        for (int ni = 0; ni < NI; ++ni) wfB[ni] = *(const f16x8*)(wp[ni] + (w + 1) * 32);
        {
            f16x8 xf[MI];
#pragma unroll
            for (int mi = 0; mi < MI; ++mi) xf[mi] = ld_act(act, mi, rl, hi, w);
            __builtin_amdgcn_s_setprio(1);
#pragma unroll
            for (int ni = 0; ni < NI; ++ni)
#pragma unroll
                for (int mi = 0; mi < MI; ++mi)
                    acc[ni][mi] = __builtin_amdgcn_mfma_f32_16x16x32_f16(wfA[ni], xf[mi], acc[ni][mi], 0, 0, 0);
            __builtin_amdgcn_s_setprio(0);
        }
        // issue global prefetch of window w+2
        if (w + 2 < NW) {
#pragma unroll
            for (int ni = 0; ni < NI; ++ni) wfA[ni] = *(const f16x8*)(wp[ni] + (w + 2) * 32);
        }
        {
            f16x8 xf[MI];
#pragma unroll
            for (int mi = 0; mi < MI; ++mi) xf[mi] = ld_act(act, mi, rl, hi, w + 1);
            __builtin_amdgcn_s_setprio(1);
#pragma unroll
            for (int ni = 0; ni < NI; ++ni)
#pragma unroll
                for (int mi = 0; mi < MI; ++mi)
                    acc[ni][mi] = __builtin_amdgcn_mfma_f32_16x16x32_f16(wfB[ni], xf[mi], acc[ni][mi], 0, 0, 0);
            __builtin_amdgcn_s_setprio(0);
        }
    }
}

// Write z (bias+relu) into act LDS [128][1024B] as 8B packs of 4 consecutive n.
template<int NI, int MI>
__device__ __forceinline__ void store_z(char* act, const float* __restrict__ bias,
                                        int wc, int lane, f32x4 (&acc)[NI][MI])
{
    const int rl = lane & 15;
    const int hi = lane >> 4;
#pragma unroll
    for (int ni = 0; ni < NI; ++ni) {
        const int n0 = wc + ni * 16 + hi * 4;
        const float4 bv = *(const float4*)(bias + n0);
#pragma unroll
        for (int mi = 0; mi < MI; ++mi) {
            const int m = mi * 16 + rl;
            f16x4 h;
            h[0] = (_Float16)fmaxf(acc[ni][mi][0] + bv.x, 0.0f);
            h[1] = (_Float16)fmaxf(acc[ni][mi][1] + bv.y, 0.0f);
            h[2] = (_Float16)fmaxf(acc[ni][mi][2] + bv.z, 0.0f);
            h[3] = (_Float16)fmaxf(acc[ni][mi][3] + bv.w, 0.0f);
            *(f16x4*)(act + m * 1024 + (((n0 >> 3) ^ (m & 7)) << 4) + (n0 & 7) * 2) = h;
        }
    }
}

__global__ __launch_bounds__(512, 2)
void fused_mlp_kernel(const float* __restrict__ x,
                      const _Float16* __restrict__ wt0, const _Float16* __restrict__ wt1,
                      const _Float16* __restrict__ wt2,
                      const float* __restrict__ b1, const float* __restrict__ b2,
                      const float* __restrict__ b3,
                      float* __restrict__ out)
{
    extern __shared__ char act[];             // 128 KB act slab only
    const int tid  = threadIdx.x;
    const int lane = tid & 63;
    const int wid  = tid >> 6;                // 0..7
    const size_t m0 = (size_t)blockIdx.x * 128;

    // ---- stage x slab f32 -> f16 into act [128 rows][1024 B stride, 512 used]
#pragma unroll
    for (int it = 0; it < 8; ++it) {
        const int c   = it * 512 + tid;       // 4096 16B-chunks
        const int row = c >> 5;
        const int c8  = c & 31;
        const float* src = x + (m0 + row) * 256 + c8 * 8;
        const float4 v0 = *(const float4*)src;
        const float4 v1 = *(const float4*)(src + 4);
        f16x8 h;
        h[0] = (_Float16)v0.x; h[1] = (_Float16)v0.y; h[2] = (_Float16)v0.z; h[3] = (_Float16)v0.w;
        h[4] = (_Float16)v1.x; h[5] = (_Float16)v1.y; h[6] = (_Float16)v1.z; h[7] = (_Float16)v1.w;
        *(f16x8*)(act + row * 1024 + ((c8 ^ (row & 7)) << 4)) = h;
    }
    __syncthreads();

    const int wc = wid * 64;                  // wave's exclusive 64-n panel (L1/L2)

    // ---- layer 1: z1 = relu(x @ W0 + b1)   [128,256]@[256,512]
    {
        f32x4 acc[4][8] = {};
        mm_reg<256, 4, 8>(act, wt0, wc, lane, acc);
        __syncthreads();                      // all waves done reading x
        store_z<4, 8>(act, b1, wc, lane, acc);
        __syncthreads();
    }

    // ---- layer 2: z2 = relu(z1 @ W1 + b2)  [128,512]@[512,512]  (in-place)
    {
        f32x4 acc[4][8] = {};
        mm_reg<512, 4, 8>(act, wt1, wc, lane, acc);
        __syncthreads();
        store_z<4, 8>(act, b2, wc, lane, acc);
        __syncthreads();
    }

    // ---- layer 3: out = z2 @ W2 + b3       [128,512]@[512,256], direct f32
    {
        const int wc3 = wid * 32;             // wave's exclusive 32-n panel
        f32x4 acc[2][8] = {};
        mm_reg<512, 2, 8>(act, wt2, wc3, lane, acc);

        const int rl = lane & 15;
        const int hi = lane >> 4;
#pragma unroll
        for (int ni = 0; ni < 2; ++ni) {
            const int n0 = wc3 + ni * 16 + hi * 4;
            const float4 bv = *(const float4*)(b3 + n0);
#pragma unroll
            for (int mi = 0; mi < 8; ++mi) {
                const size_t m = m0 + mi * 16 + rl;
                f32x4 o;
                o[0] = acc[ni][mi][0] + bv.x;
                o[1] = acc[ni][mi][1] + bv.y;
                o[2] = acc[ni][mi][2] + bv.z;
                o[3] = acc[ni][mi][3] + bv.w;
                *(f32x4*)(out + m * 256 + n0) = o;
            }
        }
    }
}

// ---------------------------------------------------------------------------
// kernel_launch — ws: [wt0 512x256 f16 | wt1 512x512 f16 | wt2 256x512 f16]
// ---------------------------------------------------------------------------
extern "C" void kernel_launch(void* const* d_in, const int* in_sizes, int n_in,
                              void* d_out, int out_size, void* d_ws, size_t ws_size,
                              hipStream_t stream)
{
    const float* x  = (const float*)d_in[0];
    const float* p0 = (const float*)d_in[1];
    const float* p1 = (const float*)d_in[2];
    const float* p2 = (const float*)d_in[3];
    const float* p3 = (const float*)d_in[4];
    const float* b1 = (const float*)d_in[5];
    const float* b2 = (const float*)d_in[6];
    const float* b3 = (const float*)d_in[7];

    char* ws = (char*)d_ws;
    _Float16* wt0 = (_Float16*)(ws);                    // 262144 B
    _Float16* wt1 = (_Float16*)(ws + 262144);           // 524288 B
    _Float16* wt2 = (_Float16*)(ws + 262144 + 524288);  // 262144 B

    synth_weights_kernel<<<2048, 256, 0, stream>>>(p0, p1, p2, p3, wt0, wt1, wt2);

    fused_mlp_kernel<<<BATCH / 128, 512, 131072, stream>>>(x, wt0, wt1, wt2, b1, b2, b3,
                                                           (float*)d_out);
}

// Round 10
// 186.823 us; speedup vs baseline: 1.8310x; 1.0047x over previous
//
#include <hip/hip_runtime.h>
#include <hip/hip_fp16.h>

typedef _Float16 f16x8 __attribute__((ext_vector_type(8)));
typedef _Float16 f16x4 __attribute__((ext_vector_type(4)));
typedef float    f32x4 __attribute__((ext_vector_type(4)));

#define BATCH 131072

// ---------------------------------------------------------------------------
// Kernel 1: synthesize W_i[k][n] = tri(dist(p_i[k], p_{i+1}[n])) / sqrt(K),
// stored TRANSPOSED as Wt[n][k] f16. k fast-varying -> coalesced writes.
// ---------------------------------------------------------------------------
__global__ void synth_weights_kernel(const float* __restrict__ p0, const float* __restrict__ p1,
                                     const float* __restrict__ p2, const float* __restrict__ p3,
                                     _Float16* __restrict__ wt0, _Float16* __restrict__ wt1,
                                     _Float16* __restrict__ wt2)
{
    int idx = blockIdx.x * blockDim.x + threadIdx.x;   // 524288 total, exact grid
    const float* A; const float* B; _Float16* Wt; float scl; int e, k, n;
    if (idx < 131072)      { A = p0; B = p1; Wt = wt0; scl = 0.0625f;              e = idx;          k = e & 255; n = e >> 8; }
    else if (idx < 393216) { A = p1; B = p2; Wt = wt1; scl = 0.04419417382415922f; e = idx - 131072; k = e & 511; n = e >> 9; }
    else                   { A = p2; B = p3; Wt = wt2; scl = 0.04419417382415922f; e = idx - 393216; k = e & 511; n = e >> 9; }
    float d2 = 0.f;
#pragma unroll
    for (int t = 0; t < 20; ++t) {
        float df = A[k * 20 + t] - B[n * 20 + t];
        d2 += df * df;
    }
    float d  = sqrtf(d2);
    float md = fmodf(d, 0.2f);                            // period 2P = 0.2, d >= 0
    float w  = 10.0f * (0.05f - fabsf(md - 0.1f)) * scl;  // AMP/P*(P-|m-P|-P/2)/sqrt(K)
    Wt[(size_t)e] = (_Float16)w;                          // e == n*K + k
}

// ---------------------------------------------------------------------------
// Fused MLP v10: v9 + WAVE STAGGER. 512 threads (8 waves), 128 rows/block,
// LDS = act slab only. Wave tile 128m x 64n (L1/L2) / 128m x 32n (L3).
//   - k-window accumulation commutes -> each wave starts its k-loop at a
//     rotated window ph = wid*(NW/8) (wrap & (NW-1)). Same-SIMD wave pairs
//     (wid, wid+4 under round-robin assignment) are NW/2 anti-phased: one
//     wave's MFMA cluster covers the other's LDS-read + prefetch phase.
//     (R6/R9 both hit the same 143 Kcyc/block wall with MfmaUtil ~24% ==
//     single-wave duty -> phase-aligned waves serialized on the matrix pipe.)
//   - wf (weights): global(L2)->reg, double-buffered one window ahead.
//   - xf (acts): single-buffered LDS reads just before the MFMA cluster.
//   - NO barriers in the k-loop; barriers only around store_z.
// frag layouts (16x16x32, HW-verified R1-R9):
//   A/B input: index = lane&15, k = (lane>>4)*8 + j
//   D (swapped: mfma(wf, xf)): m = lane&15, n = (lane>>4)*4 + q (+16*ni)
// ---------------------------------------------------------------------------
__device__ __forceinline__ f16x8 ld_act(const char* act, int mi, int rl, int hi, int w)
{
    const int row = mi * 16 + rl;
    const int c   = w * 4 + hi;
    return *(const f16x8*)(act + row * 1024 + ((c ^ (row & 7)) << 4));
}

template<int K, int NI, int MI>
__device__ __forceinline__ void mm_reg(const char* act, const _Float16* __restrict__ Wt,
                                       int wc, int lane, int wid, f32x4 (&acc)[NI][MI])
{
    constexpr int NW = K / 32;            // 32-k windows: 8 or 16 (pow2, even)
    const int rl = lane & 15;
    const int hi = lane >> 4;
    const int ph = (wid * (NW / 8)) & (NW - 1);   // per-wave start window

    const _Float16* wp[NI];
#pragma unroll
    for (int ni = 0; ni < NI; ++ni)
        wp[ni] = Wt + (size_t)(wc + ni * 16 + rl) * K + hi * 8;

    f16x8 wfA[NI], wfB[NI];
#pragma unroll
    for (int ni = 0; ni < NI; ++ni) wfA[ni] = *(const f16x8*)(wp[ni] + ph * 32);

#pragma unroll 1
    for (int w0 = 0; w0 < NW; w0 += 2) {
        const int wA = (w0 + ph) & (NW - 1);
        const int wB = (w0 + 1 + ph) & (NW - 1);
        // issue global prefetch of window wB
#pragma unroll
        for (int ni = 0; ni < NI; ++ni) wfB[ni] = *(const f16x8*)(wp[ni] + wB * 32);
        {
            f16x8 xf[MI];
#pragma unroll
            for (int mi = 0; mi < MI; ++mi) xf[mi] = ld_act(act, mi, rl, hi, wA);
            __builtin_amdgcn_s_setprio(1);
#pragma unroll
            for (int ni = 0; ni < NI; ++ni)
#pragma unroll
                for (int mi = 0; mi < MI; ++mi)
                    acc[ni][mi] = __builtin_amdgcn_mfma_f32_16x16x32_f16(wfA[ni], xf[mi], acc[ni][mi], 0, 0, 0);
            __builtin_amdgcn_s_setprio(0);
        }
        // issue global prefetch of the next iteration's first window
        if (w0 + 2 < NW) {
            const int wC = (w0 + 2 + ph) & (NW - 1);
#pragma unroll
            for (int ni = 0; ni < NI; ++ni) wfA[ni] = *(const f16x8*)(wp[ni] + wC * 32);
        }
        {
            f16x8 xf[MI];
#pragma unroll
            for (int mi = 0; mi < MI; ++mi) xf[mi] = ld_act(act, mi, rl, hi, wB);
            __builtin_amdgcn_s_setprio(1);
#pragma unroll
            for (int ni = 0; ni < NI; ++ni)
#pragma unroll
                for (int mi = 0; mi < MI; ++mi)
                    acc[ni][mi] = __builtin_amdgcn_mfma_f32_16x16x32_f16(wfB[ni], xf[mi], acc[ni][mi], 0, 0, 0);
            __builtin_amdgcn_s_setprio(0);
        }
    }
}

// Write z (bias+relu) into act LDS [128][1024B] as 8B packs of 4 consecutive n.
template<int NI, int MI>
__device__ __forceinline__ void store_z(char* act, const float* __restrict__ bias,
                                        int wc, int lane, f32x4 (&acc)[NI][MI])
{
    const int rl = lane & 15;
    const int hi = lane >> 4;
#pragma unroll
    for (int ni = 0; ni < NI; ++ni) {
        const int n0 = wc + ni * 16 + hi * 4;
        const float4 bv = *(const float4*)(bias + n0);
#pragma unroll
        for (int mi = 0; mi < MI; ++mi) {
            const int m = mi * 16 + rl;
            f16x4 h;
            h[0] = (_Float16)fmaxf(acc[ni][mi][0] + bv.x, 0.0f);
            h[1] = (_Float16)fmaxf(acc[ni][mi][1] + bv.y, 0.0f);
            h[2] = (_Float16)fmaxf(acc[ni][mi][2] + bv.z, 0.0f);
            h[3] = (_Float16)fmaxf(acc[ni][mi][3] + bv.w, 0.0f);
            *(f16x4*)(act + m * 1024 + (((n0 >> 3) ^ (m & 7)) << 4) + (n0 & 7) * 2) = h;
        }
    }
}

__global__ __launch_bounds__(512, 2)
void fused_mlp_kernel(const float* __restrict__ x,
                      const _Float16* __restrict__ wt0, const _Float16* __restrict__ wt1,
                      const _Float16* __restrict__ wt2,
                      const float* __restrict__ b1, const float* __restrict__ b2,
                      const float* __restrict__ b3,
                      float* __restrict__ out)
{
    extern __shared__ char act[];             // 128 KB act slab only
    const int tid  = threadIdx.x;
    const int lane = tid & 63;
    const int wid  = tid >> 6;                // 0..7
    const size_t m0 = (size_t)blockIdx.x * 128;

    // ---- stage x slab f32 -> f16 into act [128 rows][1024 B stride, 512 used]
#pragma unroll
    for (int it = 0; it < 8; ++it) {
        const int c   = it * 512 + tid;       // 4096 16B-chunks
        const int row = c >> 5;
        const int c8  = c & 31;
        const float* src = x + (m0 + row) * 256 + c8 * 8;
        const float4 v0 = *(const float4*)src;
        const float4 v1 = *(const float4*)(src + 4);
        f16x8 h;
        h[0] = (_Float16)v0.x; h[1] = (_Float16)v0.y; h[2] = (_Float16)v0.z; h[3] = (_Float16)v0.w;
        h[4] = (_Float16)v1.x; h[5] = (_Float16)v1.y; h[6] = (_Float16)v1.z; h[7] = (_Float16)v1.w;
        *(f16x8*)(act + row * 1024 + ((c8 ^ (row & 7)) << 4)) = h;
    }
    __syncthreads();

    const int wc = wid * 64;                  // wave's exclusive 64-n panel (L1/L2)

    // ---- layer 1: z1 = relu(x @ W0 + b1)   [128,256]@[256,512]
    {
        f32x4 acc[4][8] = {};
        mm_reg<256, 4, 8>(act, wt0, wc, lane, wid, acc);
        __syncthreads();                      // all waves done reading x
        store_z<4, 8>(act, b1, wc, lane, acc);
        __syncthreads();
    }

    // ---- layer 2: z2 = relu(z1 @ W1 + b2)  [128,512]@[512,512]  (in-place)
    {
        f32x4 acc[4][8] = {};
        mm_reg<512, 4, 8>(act, wt1, wc, lane, wid, acc);
        __syncthreads();
        store_z<4, 8>(act, b2, wc, lane, acc);
        __syncthreads();
    }

    // ---- layer 3: out = z2 @ W2 + b3       [128,512]@[512,256], direct f32
    {
        const int wc3 = wid * 32;             // wave's exclusive 32-n panel
        f32x4 acc[2][8] = {};
        mm_reg<512, 2, 8>(act, wt2, wc3, lane, wid, acc);

        const int rl = lane & 15;
        const int hi = lane >> 4;
#pragma unroll
        for (int ni = 0; ni < 2; ++ni) {
            const int n0 = wc3 + ni * 16 + hi * 4;
            const float4 bv = *(const float4*)(b3 + n0);
#pragma unroll
            for (int mi = 0; mi < 8; ++mi) {
                const size_t m = m0 + mi * 16 + rl;
                f32x4 o;
                o[0] = acc[ni][mi][0] + bv.x;
                o[1] = acc[ni][mi][1] + bv.y;
                o[2] = acc[ni][mi][2] + bv.z;
                o[3] = acc[ni][mi][3] + bv.w;
                *(f32x4*)(out + m * 256 + n0) = o;
            }
        }
    }
}

// ---------------------------------------------------------------------------
// kernel_launch — ws: [wt0 512x256 f16 | wt1 512x512 f16 | wt2 256x512 f16]
// ---------------------------------------------------------------------------
extern "C" void kernel_launch(void* const* d_in, const int* in_sizes, int n_in,
                              void* d_out, int out_size, void* d_ws, size_t ws_size,
                              hipStream_t stream)
{
    const float* x  = (const float*)d_in[0];
    const float* p0 = (const float*)d_in[1];
    const float* p1 = (const float*)d_in[2];
    const float* p2 = (const float*)d_in[3];
    const float* p3 = (const float*)d_in[4];
    const float* b1 = (const float*)d_in[5];
    const float* b2 = (const float*)d_in[6];
    const float* b3 = (const float*)d_in[7];

    char* ws = (char*)d_ws;
    _Float16* wt0 = (_Float16*)(ws);                    // 262144 B
    _Float16* wt1 = (_Float16*)(ws + 262144);           // 524288 B
    _Float16* wt2 = (_Float16*)(ws + 262144 + 524288);  // 262144 B

    synth_weights_kernel<<<2048, 256, 0, stream>>>(p0, p1, p2, p3, wt0, wt1, wt2);

    fused_mlp_kernel<<<BATCH / 128, 512, 131072, stream>>>(x, wt0, wt1, wt2, b1, b2, b3,
                                                           (float*)d_out);
}

// Round 11
// 159.935 us; speedup vs baseline: 2.1389x; 1.1681x over previous
//
#include <hip/hip_runtime.h>
#include <hip/hip_fp16.h>

typedef _Float16 f16x8 __attribute__((ext_vector_type(8)));
typedef _Float16 f16x4 __attribute__((ext_vector_type(4)));
typedef float    f32x4 __attribute__((ext_vector_type(4)));

#define BATCH 131072

// ---------------------------------------------------------------------------
// Kernel 1: synthesize weights DIRECTLY IN MFMA FRAGMENT ORDER (per-layer
// blobs). Element e of a blob maps to (wid, w, ni, lane, j):
//   byte_off = ((wid*NW + w)*NI + ni)*1024 + lane*16 + j*2
//   n = wid*PANEL + ni*16 + (lane&15),  k = w*32 + (lane>>4)*8 + j
// so each wave's wf load = ONE contiguous 1KB transaction (no gathers).
// W[k][n] = tri(dist(p_i[k], p_{i+1}[n])) / sqrt(K).
// ---------------------------------------------------------------------------
__global__ void synth_weights_kernel(const float* __restrict__ p0, const float* __restrict__ p1,
                                     const float* __restrict__ p2, const float* __restrict__ p3,
                                     _Float16* __restrict__ blob0, _Float16* __restrict__ blob1,
                                     _Float16* __restrict__ blob2)
{
    const int idx = blockIdx.x * blockDim.x + threadIdx.x;   // 524288 total
    const float* A; const float* B; _Float16* Wt; float scl; int e, n, k;
    if (idx < 131072) {            // L1: K=256, NW=8, NI=4, PANEL=64
        A = p0; B = p1; Wt = blob0; scl = 0.0625f; e = idx;
        const int j = e & 7, lane = (e >> 3) & 63, t = e >> 9;
        const int ni = t & 3, pw = t >> 2, w = pw & 7, wid = pw >> 3;
        n = wid * 64 + ni * 16 + (lane & 15);
        k = w * 32 + ((lane >> 4) << 3) + j;
    } else if (idx < 393216) {     // L2: K=512, NW=16, NI=4, PANEL=64
        A = p1; B = p2; Wt = blob1; scl = 0.04419417382415922f; e = idx - 131072;
        const int j = e & 7, lane = (e >> 3) & 63, t = e >> 9;
        const int ni = t & 3, pw = t >> 2, w = pw & 15, wid = pw >> 4;
        n = wid * 64 + ni * 16 + (lane & 15);
        k = w * 32 + ((lane >> 4) << 3) + j;
    } else {                       // L3: K=512, NW=16, NI=2, PANEL=32
        A = p2; B = p3; Wt = blob2; scl = 0.04419417382415922f; e = idx - 393216;
        const int j = e & 7, lane = (e >> 3) & 63, t = e >> 9;
        const int ni = t & 1, pw = t >> 1, w = pw & 15, wid = pw >> 4;
        n = wid * 32 + ni * 16 + (lane & 15);
        k = w * 32 + ((lane >> 4) << 3) + j;
    }
    float d2 = 0.f;
#pragma unroll
    for (int t = 0; t < 20; ++t) {
        float df = A[k * 20 + t] - B[n * 20 + t];
        d2 += df * df;
    }
    float d  = sqrtf(d2);
    float md = fmodf(d, 0.2f);                            // period 2P = 0.2, d >= 0
    float w  = 10.0f * (0.05f - fabsf(md - 0.1f)) * scl;  // AMP/P*(P-|m-P|-P/2)/sqrt(K)
    Wt[(size_t)e] = (_Float16)w;
}

// ---------------------------------------------------------------------------
// Fused MLP v11: R10 structure + fragment-ordered COALESCED weight loads.
// 512 threads (8 waves), 128 rows/block, LDS = act slab only (128 KB).
// Wave tile 128m x 64n (L1/L2) / 128m x 32n (L3); B-redundancy = 1.
//   - wf: global(L2)->reg, contiguous 1KB/wave/load, double-buffered one
//     window ahead; per-wave start-window stagger ph spreads L2 requests.
//   - xf: single-buffered LDS reads; MFMA cluster is mi-OUTER so the first
//     MFMA group waits only on xf[0] (fine-grained lgkmcnt).
//   - NO barriers in the k-loop; barriers only around store_z.
// frag layouts (16x16x32, HW-verified R1-R10):
//   A/B input: index = lane&15, k = (lane>>4)*8 + j
//   D (swapped: mfma(wf, xf)): m = lane&15, n = (lane>>4)*4 + q (+16*ni)
// ---------------------------------------------------------------------------
__device__ __forceinline__ f16x8 ld_act(const char* act, int mi, int rl, int hi, int w)
{
    const int row = mi * 16 + rl;
    const int c   = w * 4 + hi;
    return *(const f16x8*)(act + row * 1024 + ((c ^ (row & 7)) << 4));
}

template<int NW, int NI, int MI>
__device__ __forceinline__ void mm_reg(const char* act, const _Float16* __restrict__ blob,
                                       int lane, int wid, f32x4 (&acc)[NI][MI])
{
    const int rl = lane & 15;
    const int hi = lane >> 4;
    const int ph = (wid * (NW / 8)) & (NW - 1);   // per-wave start window

    // wave's panel base: contiguous NW*NI KB; window w at +(w*NI)*1024
    const char* wbase = (const char*)blob + ((size_t)wid * NW * NI) * 1024 + lane * 16;

    f16x8 wfA[NI], wfB[NI];
#pragma unroll
    for (int ni = 0; ni < NI; ++ni)
        wfA[ni] = *(const f16x8*)(wbase + (ph * NI + ni) * 1024);

#pragma unroll 1
    for (int w0 = 0; w0 < NW; w0 += 2) {
        const int wA = (w0 + ph) & (NW - 1);
        const int wB = (w0 + 1 + ph) & (NW - 1);
        // prefetch window wB (contiguous 4KB stream per wave)
#pragma unroll
        for (int ni = 0; ni < NI; ++ni)
            wfB[ni] = *(const f16x8*)(wbase + (wB * NI + ni) * 1024);
        {
            f16x8 xf[MI];
#pragma unroll
            for (int mi = 0; mi < MI; ++mi) xf[mi] = ld_act(act, mi, rl, hi, wA);
            __builtin_amdgcn_s_setprio(1);
#pragma unroll
            for (int mi = 0; mi < MI; ++mi)
#pragma unroll
                for (int ni = 0; ni < NI; ++ni)
                    acc[ni][mi] = __builtin_amdgcn_mfma_f32_16x16x32_f16(wfA[ni], xf[mi], acc[ni][mi], 0, 0, 0);
            __builtin_amdgcn_s_setprio(0);
        }
        // prefetch next iteration's first window
        if (w0 + 2 < NW) {
            const int wC = (w0 + 2 + ph) & (NW - 1);
#pragma unroll
            for (int ni = 0; ni < NI; ++ni)
                wfA[ni] = *(const f16x8*)(wbase + (wC * NI + ni) * 1024);
        }
        {
            f16x8 xf[MI];
#pragma unroll
            for (int mi = 0; mi < MI; ++mi) xf[mi] = ld_act(act, mi, rl, hi, wB);
            __builtin_amdgcn_s_setprio(1);
#pragma unroll
            for (int mi = 0; mi < MI; ++mi)
#pragma unroll
                for (int ni = 0; ni < NI; ++ni)
                    acc[ni][mi] = __builtin_amdgcn_mfma_f32_16x16x32_f16(wfB[ni], xf[mi], acc[ni][mi], 0, 0, 0);
            __builtin_amdgcn_s_setprio(0);
        }
    }
}

// Write z (bias+relu) into act LDS [128][1024B] as 8B packs of 4 consecutive n.
template<int NI, int MI>
__device__ __forceinline__ void store_z(char* act, const float* __restrict__ bias,
                                        int wc, int lane, f32x4 (&acc)[NI][MI])
{
    const int rl = lane & 15;
    const int hi = lane >> 4;
#pragma unroll
    for (int ni = 0; ni < NI; ++ni) {
        const int n0 = wc + ni * 16 + hi * 4;
        const float4 bv = *(const float4*)(bias + n0);
#pragma unroll
        for (int mi = 0; mi < MI; ++mi) {
            const int m = mi * 16 + rl;
            f16x4 h;
            h[0] = (_Float16)fmaxf(acc[ni][mi][0] + bv.x, 0.0f);
            h[1] = (_Float16)fmaxf(acc[ni][mi][1] + bv.y, 0.0f);
            h[2] = (_Float16)fmaxf(acc[ni][mi][2] + bv.z, 0.0f);
            h[3] = (_Float16)fmaxf(acc[ni][mi][3] + bv.w, 0.0f);
            *(f16x4*)(act + m * 1024 + (((n0 >> 3) ^ (m & 7)) << 4) + (n0 & 7) * 2) = h;
        }
    }
}

__global__ __launch_bounds__(512, 2)
void fused_mlp_kernel(const float* __restrict__ x,
                      const _Float16* __restrict__ blob0, const _Float16* __restrict__ blob1,
                      const _Float16* __restrict__ blob2,
                      const float* __restrict__ b1, const float* __restrict__ b2,
                      const float* __restrict__ b3,
                      float* __restrict__ out)
{
    extern __shared__ char act[];             // 128 KB act slab only
    const int tid  = threadIdx.x;
    const int lane = tid & 63;
    const int wid  = tid >> 6;                // 0..7
    const size_t m0 = (size_t)blockIdx.x * 128;

    // ---- stage x slab f32 -> f16 into act [128 rows][1024 B stride, 512 used]
#pragma unroll
    for (int it = 0; it < 8; ++it) {
        const int c   = it * 512 + tid;       // 4096 16B-chunks
        const int row = c >> 5;
        const int c8  = c & 31;
        const float* src = x + (m0 + row) * 256 + c8 * 8;
        const float4 v0 = *(const float4*)src;
        const float4 v1 = *(const float4*)(src + 4);
        f16x8 h;
        h[0] = (_Float16)v0.x; h[1] = (_Float16)v0.y; h[2] = (_Float16)v0.z; h[3] = (_Float16)v0.w;
        h[4] = (_Float16)v1.x; h[5] = (_Float16)v1.y; h[6] = (_Float16)v1.z; h[7] = (_Float16)v1.w;
        *(f16x8*)(act + row * 1024 + ((c8 ^ (row & 7)) << 4)) = h;
    }
    __syncthreads();

    const int wc = wid * 64;                  // wave's exclusive 64-n panel (L1/L2)

    // ---- layer 1: z1 = relu(x @ W0 + b1)   [128,256]@[256,512]
    {
        f32x4 acc[4][8] = {};
        mm_reg<8, 4, 8>(act, blob0, lane, wid, acc);
        __syncthreads();                      // all waves done reading x
        store_z<4, 8>(act, b1, wc, lane, acc);
        __syncthreads();
    }

    // ---- layer 2: z2 = relu(z1 @ W1 + b2)  [128,512]@[512,512]  (in-place)
    {
        f32x4 acc[4][8] = {};
        mm_reg<16, 4, 8>(act, blob1, lane, wid, acc);
        __syncthreads();
        store_z<4, 8>(act, b2, wc, lane, acc);
        __syncthreads();
    }

    // ---- layer 3: out = z2 @ W2 + b3       [128,512]@[512,256], direct f32
    {
        const int wc3 = wid * 32;             // wave's exclusive 32-n panel
        f32x4 acc[2][8] = {};
        mm_reg<16, 2, 8>(act, blob2, lane, wid, acc);

        const int rl = lane & 15;
        const int hi = lane >> 4;
#pragma unroll
        for (int ni = 0; ni < 2; ++ni) {
            const int n0 = wc3 + ni * 16 + hi * 4;
            const float4 bv = *(const float4*)(b3 + n0);
#pragma unroll
            for (int mi = 0; mi < 8; ++mi) {
                const size_t m = m0 + mi * 16 + rl;
                f32x4 o;
                o[0] = acc[ni][mi][0] + bv.x;
                o[1] = acc[ni][mi][1] + bv.y;
                o[2] = acc[ni][mi][2] + bv.z;
                o[3] = acc[ni][mi][3] + bv.w;
                *(f32x4*)(out + m * 256 + n0) = o;
            }
        }
    }
}

// ---------------------------------------------------------------------------
// kernel_launch — ws: [blob0 256KB | blob1 512KB | blob2 256KB]
// ---------------------------------------------------------------------------
extern "C" void kernel_launch(void* const* d_in, const int* in_sizes, int n_in,
                              void* d_out, int out_size, void* d_ws, size_t ws_size,
                              hipStream_t stream)
{
    const float* x  = (const float*)d_in[0];
    const float* p0 = (const float*)d_in[1];
    const float* p1 = (const float*)d_in[2];
    const float* p2 = (const float*)d_in[3];
    const float* p3 = (const float*)d_in[4];
    const float* b1 = (const float*)d_in[5];
    const float* b2 = (const float*)d_in[6];
    const float* b3 = (const float*)d_in[7];

    char* ws = (char*)d_ws;
    _Float16* blob0 = (_Float16*)(ws);                    // 262144 B
    _Float16* blob1 = (_Float16*)(ws + 262144);           // 524288 B
    _Float16* blob2 = (_Float16*)(ws + 262144 + 524288);  // 262144 B

    synth_weights_kernel<<<2048, 256, 0, stream>>>(p0, p1, p2, p3, blob0, blob1, blob2);

    fused_mlp_kernel<<<BATCH / 128, 512, 131072, stream>>>(x, blob0, blob1, blob2,
                                                           b1, b2, b3, (float*)d_out);
}